// Round 1
// 403.416 us; speedup vs baseline: 1.0001x; 1.0001x over previous
//
#include <hip/hip_runtime.h>
#include <stdint.h>
#include <stddef.h>

#define K_DIM 4096
#define N_DIM 4096
#define BM 128
#define BN 256
#define BK 128                    // bytes of K per tile (two 16x16x64 substeps)
#define NT (K_DIM / BK)           // 32 K-tiles
#define SLOT_A (BM * BK)          // 16 KB
#define SLOT_B (BN * BK)          // 32 KB
#define SLOT (SLOT_A + SLOT_B)    // 48 KB
#define LDS_BYTES (3 * SLOT)      // 144 KB ring-3

typedef int v4i __attribute__((ext_vector_type(4)));
typedef uint32_t v4u __attribute__((ext_vector_type(4)));

__device__ __forceinline__ void load_lds16(const void* gp, void* lp) {
  __builtin_amdgcn_global_load_lds(
      (__attribute__((address_space(1))) void*)(uintptr_t)gp,
      (__attribute__((address_space(3))) void*)(uintptr_t)lp,
      16, 0, 0);
}

__device__ __forceinline__ uint32_t pack4(int a, int b, int c, int d) {
  return (uint32_t)(uint8_t)a | ((uint32_t)(uint8_t)b << 8) |
         ((uint32_t)(uint8_t)c << 16) | ((uint32_t)(uint8_t)d << 24);
}

// ---------------- Kernel 0: pack weight int32 -> int8 ----------------------
__global__ __launch_bounds__(256) void pack_w_kernel(
    const int4* __restrict__ w32, v4u* __restrict__ w8, int n16) {
  int i = blockIdx.x * 256 + threadIdx.x;
  if (i >= n16) return;
  int4 a = w32[i * 4 + 0], b = w32[i * 4 + 1], c = w32[i * 4 + 2], d = w32[i * 4 + 3];
  v4u o;
  o.x = pack4(a.x, a.y, a.z, a.w);
  o.y = pack4(b.x, b.y, b.z, b.w);
  o.z = pack4(c.x, c.y, c.z, c.w);
  o.w = pack4(d.x, d.y, d.z, d.w);
  w8[i] = o;
}

// ---------------- Kernel 1: quantize fp32 -> int8 --------------------------
// Exact fp32 division + RNE to match jnp.round(x / INPUT_SCALE).
__global__ __launch_bounds__(256) void quant_kernel(
    const float4* __restrict__ x, v4u* __restrict__ xq, int n16) {
  int i = blockIdx.x * 256 + threadIdx.x;
  if (i >= n16) return;
  v4u o;
#pragma unroll
  for (int j = 0; j < 4; ++j) {
    float4 v = x[i * 4 + j];
    float r0 = fminf(fmaxf(rintf(v.x / 0.05f), -128.f), 127.f);
    float r1 = fminf(fmaxf(rintf(v.y / 0.05f), -128.f), 127.f);
    float r2 = fminf(fmaxf(rintf(v.z / 0.05f), -128.f), 127.f);
    float r3 = fminf(fmaxf(rintf(v.w / 0.05f), -128.f), 127.f);
    o[j] = pack4((int)r0, (int)r1, (int)r2, (int)r3);
  }
  xq[i] = o;
}

// ---------------- Kernel 2: int8 GEMM, ring-3 counted-vmcnt pipeline -------
// 128x256 tile, 8 waves (2M x 4N, wave tile 64x64). BK=128 B -> 2 substeps of
// 16 x v_mfma_i32_16x16x64_i8 per tile (2 phases x 16 MFMA).
//
// LDS: ring of 3 K-tile slots (48 KB each). While computing tile t from slot
// t%3, stage tile t+2 into slot (t+2)%3 via global_load_lds(16B). Slot
// (t+2)%3's previous occupant (t-1) was fully consumed before tile t began
// (per-wave lgkm waits precede the MFMAs, which precede the tile-final
// barrier) -> deterministically race-free, ~2-tile issue->use lead.
//
// vmcnt discipline (T4): 6 staging loads/thread/tile (A:2, B:4). At each tile
// boundary wait vmcnt(6) -> forces tile t+1's loads complete while t+2's 6
// stay in flight. Raw s_barrier (no vmcnt(0) drain) + s_setprio around MFMA
// clusters (T5). sched_barrier(0) only at barrier boundaries.
//
// LDS swizzle (verified, 0 bank conflicts): element block (row, kv) at v4i
// index row*8 + (kv ^ (row&7)); staging achieves it by permuting per-lane
// GLOBAL source addresses (LDS dst of global_load_lds is rigid).
//
// XCD swizzle: 1024 blocks = 64 m x 16 n; 2 n-blocks per XCD (2 MB of B
// L2-resident), all XCDs sweep m together so the A panel is LLC-shared.
__global__ __launch_bounds__(512, 2) void gemm_i8_kernel(
    const int8_t* __restrict__ A,     // [M, K] quantized activations
    const int8_t* __restrict__ B,     // [N, K] weight (packed int8)
    const float* __restrict__ bias,   // [N]
    float* __restrict__ C,            // [M, N]
    int M) {
  extern __shared__ __align__(16) int8_t lds[];

  const int tid  = threadIdx.x;
  const int lane = tid & 63;
  const int wave = tid >> 6;
  const int wm   = wave >> 2;   // 0..1  (64-row band)
  const int wn   = wave & 3;    // 0..3  (64-col band)
  const int quad = lane >> 4;
  const int lrow = lane & 15;
  const int rx7  = lrow & 7;

  const int bid   = blockIdx.x;
  const int xcd   = bid & 7;
  const int slot  = bid >> 3;            // 0..127
  const int n_blk = xcd * 2 + (slot & 1);
  const int m_blk = slot >> 1;           // 0..63
  const int m0 = m_blk * BM;
  const int n0 = n_blk * BN;

  // Staging source pointers. Chunk-linear index c = q*512 + tid over the
  // slot; row = c>>3, phys chunk = c&7, logical chunk = (c&7) ^ (row&7).
  const int8_t* ag[2];
#pragma unroll
  for (int q = 0; q < 2; ++q) {
    int c = q * 512 + tid;
    int row = c >> 3;
    int lc = (c & 7) ^ (row & 7);
    ag[q] = A + (size_t)(m0 + row) * K_DIM + lc * 16;
  }
  const int8_t* bg[4];
#pragma unroll
  for (int q = 0; q < 4; ++q) {
    int c = q * 512 + tid;
    int row = c >> 3;
    int lc = (c & 7) ^ (row & 7);
    bg[q] = B + (size_t)(n0 + row) * K_DIM + lc * 16;
  }

  int sb0 = 0, sb1 = SLOT, sb2 = 2 * SLOT;  // read / next / stage-target

  // Prologue: stage tile 0 -> sb0, tile 1 -> sb1 (12 loads), wait oldest 6.
#pragma unroll
  for (int q = 0; q < 2; ++q)
    load_lds16(ag[q], lds + sb0 + (q * 512 + tid) * 16);
#pragma unroll
  for (int q = 0; q < 4; ++q)
    load_lds16(bg[q], lds + sb0 + SLOT_A + (q * 512 + tid) * 16);
#pragma unroll
  for (int q = 0; q < 2; ++q)
    load_lds16(ag[q] + BK, lds + sb1 + (q * 512 + tid) * 16);
#pragma unroll
  for (int q = 0; q < 4; ++q)
    load_lds16(bg[q] + BK, lds + sb1 + SLOT_A + (q * 512 + tid) * 16);
#pragma unroll
  for (int q = 0; q < 2; ++q) ag[q] += 2 * BK;
#pragma unroll
  for (int q = 0; q < 4; ++q) bg[q] += 2 * BK;

  asm volatile("s_waitcnt vmcnt(6)" ::: "memory");
  __builtin_amdgcn_s_barrier();
  __builtin_amdgcn_sched_barrier(0);

  v4i acc[4][4] = {};

#define MFMA16()                                                        \
  _Pragma("unroll") for (int i = 0; i < 4; ++i)                          \
    _Pragma("unroll") for (int j = 0; j < 4; ++j)                        \
      acc[i][j] = __builtin_amdgcn_mfma_i32_16x16x64_i8(af[i], bf[j],    \
                                                        acc[i][j], 0, 0, 0);

#pragma unroll 1
  for (int t = 0; t < NT; ++t) {
    const v4i* A4 = (const v4i*)(lds + sb0);
    const v4i* B4 = (const v4i*)(lds + sb0 + SLOT_A);
    const bool pf = (t < NT - 2);

    // ---- phase 1: substep 0 (logical chunks 0..3) ----
    v4i af[4], bf[4];
#pragma unroll
    for (int i = 0; i < 4; ++i)
      af[i] = A4[(wm * 64 + i * 16 + lrow) * 8 + (quad ^ rx7)];
#pragma unroll
    for (int j = 0; j < 4; ++j)
      bf[j] = B4[(wn * 64 + j * 16 + lrow) * 8 + (quad ^ rx7)];
    if (pf) {
      load_lds16(ag[0], lds + sb2 + (0 * 512 + tid) * 16);
      load_lds16(ag[1], lds + sb2 + (1 * 512 + tid) * 16);
      load_lds16(bg[0], lds + sb2 + SLOT_A + (0 * 512 + tid) * 16);
    }
    __builtin_amdgcn_s_barrier();
    __builtin_amdgcn_sched_barrier(0);
    __builtin_amdgcn_s_setprio(1);
    MFMA16();
    __builtin_amdgcn_s_setprio(0);
    __builtin_amdgcn_sched_barrier(0);
    __builtin_amdgcn_s_barrier();

    // ---- phase 2: substep 1 (logical chunks 4..7) ----
#pragma unroll
    for (int i = 0; i < 4; ++i)
      af[i] = A4[(wm * 64 + i * 16 + lrow) * 8 + ((4 + quad) ^ rx7)];
#pragma unroll
    for (int j = 0; j < 4; ++j)
      bf[j] = B4[(wn * 64 + j * 16 + lrow) * 8 + ((4 + quad) ^ rx7)];
    if (pf) {
      load_lds16(bg[1], lds + sb2 + SLOT_A + (1 * 512 + tid) * 16);
      load_lds16(bg[2], lds + sb2 + SLOT_A + (2 * 512 + tid) * 16);
      load_lds16(bg[3], lds + sb2 + SLOT_A + (3 * 512 + tid) * 16);
      ag[0] += BK; ag[1] += BK;
      bg[0] += BK; bg[1] += BK; bg[2] += BK; bg[3] += BK;
    }
    __builtin_amdgcn_s_barrier();
    __builtin_amdgcn_sched_barrier(0);
    __builtin_amdgcn_s_setprio(1);
    MFMA16();
    __builtin_amdgcn_s_setprio(0);
    __builtin_amdgcn_sched_barrier(0);
    // Tile boundary: force tile t+1 landed; keep t+2's 6 loads in flight.
    if (pf) {
      asm volatile("s_waitcnt vmcnt(6)" ::: "memory");
    } else if (t < NT - 1) {
      asm volatile("s_waitcnt vmcnt(0)" ::: "memory");
    }
    __builtin_amdgcn_s_barrier();
    __builtin_amdgcn_sched_barrier(0);

    int tmp = sb0; sb0 = sb1; sb1 = sb2; sb2 = tmp;  // rotate ring
  }
#undef MFMA16

  // Epilogue: y = 0.01 * acc + bias[n]
#pragma unroll
  for (int j = 0; j < 4; ++j) {
    const int n = n0 + wn * 64 + j * 16 + lrow;
    const float bn = bias[n];
#pragma unroll
    for (int i = 0; i < 4; ++i) {
      const int mb = m0 + wm * 64 + i * 16 + quad * 4;
#pragma unroll
      for (int r = 0; r < 4; ++r)
        C[(size_t)(mb + r) * N_DIM + n] = 0.01f * (float)acc[i][j][r] + bn;
    }
  }
}

extern "C" void kernel_launch(void* const* d_in, const int* in_sizes, int n_in,
                              void* d_out, int out_size, void* d_ws, size_t ws_size,
                              hipStream_t stream) {
  static bool inited = false;
  if (!inited) {
    (void)hipFuncSetAttribute(reinterpret_cast<const void*>(gemm_i8_kernel),
                              hipFuncAttributeMaxDynamicSharedMemorySize,
                              LDS_BYTES);
    inited = true;
  }

  const float* x    = (const float*)d_in[0];
  const int*   w32  = (const int*)d_in[1];   // harness stores int8 input as int32
  const float* bias = (const float*)d_in[2];
  float* out = (float*)d_out;
  const int M = in_sizes[0] / K_DIM;  // 8192

  int8_t* xq = (int8_t*)d_ws;                              // M*K
  int8_t* wq = (int8_t*)d_ws + (size_t)M * K_DIM;          // N*K

  const int nw16 = (N_DIM * K_DIM) / 16;
  pack_w_kernel<<<(nw16 + 255) / 256, 256, 0, stream>>>(
      (const int4*)w32, (v4u*)wq, nw16);

  const int n16 = (M * K_DIM) / 16;
  quant_kernel<<<(n16 + 255) / 256, 256, 0, stream>>>(
      (const float4*)x, (v4u*)xq, n16);

  const int nblocks = (M / BM) * (N_DIM / BN);  // 1024
  gemm_i8_kernel<<<nblocks, 512, LDS_BYTES, stream>>>(xq, wq, bias, out, M);
}